// Round 1
// baseline (348.291 us; speedup 1.0000x reference)
//
#include <hip/hip_runtime.h>
#include <utility>

#define NW 10
#define NL 4

// ---------- gate helpers: state = 16 complex amps per lane (sr/si), 64 lanes/wave ----------
// amplitude index i = lane*16 + j ; state bit b<4 -> local bit b of j ; b>=4 -> lane bit b-4.
// wire w (PennyLane, wire0=MSB) <-> state bit (9-w).

template<int B>
__device__ __forceinline__ void rot_local(float (&sr)[16], float (&si)[16], const float* m) {
    const float u00r = m[0], u00i = m[1], u01r = m[2], u01i = m[3];
    const float u10r = m[4], u10i = m[5], u11r = m[6], u11i = m[7];
#pragma unroll
    for (int j0 = 0; j0 < 16; ++j0) {
        if (j0 & (1 << B)) continue;
        const int j1 = j0 | (1 << B);
        const float a0r = sr[j0], a0i = si[j0], a1r = sr[j1], a1i = si[j1];
        sr[j0] = u00r*a0r - u00i*a0i + u01r*a1r - u01i*a1i;
        si[j0] = u00r*a0i + u00i*a0r + u01r*a1i + u01i*a1r;
        sr[j1] = u10r*a0r - u10i*a0i + u11r*a1r - u11i*a1i;
        si[j1] = u10r*a0i + u10i*a0r + u11r*a1i + u11i*a1r;
    }
}

template<int LB>   // cross-lane 1q gate on lane bit LB (state bit LB+4)
__device__ __forceinline__ void rot_xlane(float (&sr)[16], float (&si)[16], const float* m, int lane) {
    const bool hi = (lane >> LB) & 1;
    // my-coefficient / other-coefficient:
    // hi=0 (I hold a0): new = u00*mine + u01*other ; hi=1: new = u11*mine + u10*other
    const float cmr = hi ? m[6] : m[0];
    const float cmi = hi ? m[7] : m[1];
    const float cor = hi ? m[4] : m[2];
    const float coi = hi ? m[5] : m[3];
#pragma unroll
    for (int j = 0; j < 16; ++j) {
        const float pr  = __shfl_xor(sr[j], 1 << LB, 64);
        const float pim = __shfl_xor(si[j], 1 << LB, 64);
        const float nr = cmr*sr[j] - cmi*si[j] + cor*pr  - coi*pim;
        const float ni = cmr*si[j] + cmi*sr[j] + cor*pim + coi*pr;
        sr[j] = nr; si[j] = ni;
    }
}

template<int CB, int TB>  // CNOT: control state-bit CB, target state-bit TB (pure permutation)
__device__ __forceinline__ void cnot_g(float (&sr)[16], float (&si)[16], int lane) {
    if constexpr (CB < 4 && TB < 4) {
        // both local: compile-time register swap (free after renaming)
#pragma unroll
        for (int j = 0; j < 16; ++j) {
            if ((j & (1 << CB)) && !(j & (1 << TB))) {
                const int k = j | (1 << TB);
                float t;
                t = sr[j]; sr[j] = sr[k]; sr[k] = t;
                t = si[j]; si[j] = si[k]; si[k] = t;
            }
        }
    } else if constexpr (CB >= 4 && TB < 4) {
        // control = lane bit, target local: predicated local swap (cndmask)
        const bool ctrl = (lane >> (CB - 4)) & 1;
#pragma unroll
        for (int j = 0; j < 16; ++j) {
            if (!(j & (1 << TB))) {
                const int k = j | (1 << TB);
                const float r0 = sr[j], r1 = sr[k];
                const float i0 = si[j], i1 = si[k];
                sr[j] = ctrl ? r1 : r0; sr[k] = ctrl ? r0 : r1;
                si[j] = ctrl ? i1 : i0; si[k] = ctrl ? i0 : i1;
            }
        }
    } else if constexpr (CB < 4 && TB >= 4) {
        // control local, target = lane bit: only ctrl=1 slots exchange (unconditional swap)
#pragma unroll
        for (int j = 0; j < 16; ++j) {
            if (j & (1 << CB)) {
                sr[j] = __shfl_xor(sr[j], 1 << (TB - 4), 64);
                si[j] = __shfl_xor(si[j], 1 << (TB - 4), 64);
            }
        }
    } else {
        // both lane bits: lanes with ctrl=1 pull from partner (ds_bpermute)
        const bool ctrl = (lane >> (CB - 4)) & 1;
        const int src = ctrl ? (lane ^ (1 << (TB - 4))) : lane;
#pragma unroll
        for (int j = 0; j < 16; ++j) {
            sr[j] = __shfl(sr[j], src, 64);
            si[j] = __shfl(si[j], src, 64);
        }
    }
}

template<int R, int... Ws>
__device__ __forceinline__ void ring_impl(float (&sr)[16], float (&si)[16], int lane,
                                          std::integer_sequence<int, Ws...>) {
    // CNOT(control=w, target=(w+R)%10), applied in w order (comma-fold is left-to-right)
    (cnot_g<9 - Ws, 9 - ((Ws + R) % 10)>(sr, si, lane), ...);
}

template<int R>
__device__ __forceinline__ void ring(float (&sr)[16], float (&si)[16], int lane) {
    ring_impl<R>(sr, si, lane, std::make_integer_sequence<int, NW>{});
}

__global__ __launch_bounds__(256) void vqc_kernel(const float* __restrict__ X,
                                                  const float* __restrict__ W,
                                                  const float* __restrict__ bias,
                                                  float* __restrict__ out,
                                                  int n_samples) {
    __shared__ float rotm[NL * NW * 8];
    const int t = threadIdx.x;

    // --- per-block Rot-matrix prep (weights are batch-uniform; redundant per block, negligible) ---
    if (t < NL * NW) {
        const float phi = W[t * 3 + 0], th = W[t * 3 + 1], om = W[t * 3 + 2];
        float sh, ch; sincosf(0.5f * th, &sh, &ch);
        float s0, c0; sincosf(-0.5f * (phi + om), &s0, &c0);  // e^{-i(phi+om)/2}
        float s1, c1; sincosf( 0.5f * (phi - om), &s1, &c1);  // e^{+i(phi-om)/2}
        float* m = rotm + t * 8;
        m[0] =  c0 * ch; m[1] =  s0 * ch;   // m00 = e^{-i(phi+om)/2} cos
        m[2] = -c1 * sh; m[3] = -s1 * sh;   // m01 = -e^{+i(phi-om)/2} sin
        m[4] =  c1 * sh; m[5] = -s1 * sh;   // m10 = e^{-i(phi-om)/2} sin
        m[6] =  c0 * ch; m[7] = -s0 * ch;   // m11 = e^{+i(phi+om)/2} cos
    }
    __syncthreads();

    const int wave = (blockIdx.x * blockDim.x + t) >> 6;  // one wave per sample
    const int lane = t & 63;
    if (wave >= n_samples) return;

    // --- angle encoding: RY(x_w*pi/2) on |0..0> = real product state, built directly ---
    const float* xp = X + wave * NW;
    float cw[NW], sw[NW];
#pragma unroll
    for (int w = 0; w < NW; ++w) {
        __sincosf(xp[w] * 0.78539816339744831f, &sw[w], &cw[w]);  // theta/2 = x*pi/4
    }
    float sr[16], si[16];
#pragma unroll
    for (int j = 0; j < 16; ++j) {
        const int idx = (lane << 4) | j;
        float p = 1.0f;
#pragma unroll
        for (int w = 0; w < NW; ++w) {
            p *= ((idx >> (9 - w)) & 1) ? sw[w] : cw[w];
        }
        sr[j] = p; si[j] = 0.0f;
    }

    // --- 4 StronglyEntanglingLayers: Rot on wires 0..9, then CNOT ring with r = l+1 ---
#pragma unroll 1
    for (int l = 0; l < NL; ++l) {
        const float* lm = rotm + l * (NW * 8);
        rot_xlane<5>(sr, si, lm + 0,  lane);   // wire 0 -> state bit 9
        rot_xlane<4>(sr, si, lm + 8,  lane);
        rot_xlane<3>(sr, si, lm + 16, lane);
        rot_xlane<2>(sr, si, lm + 24, lane);
        rot_xlane<1>(sr, si, lm + 32, lane);
        rot_xlane<0>(sr, si, lm + 40, lane);   // wire 5 -> state bit 4
        rot_local<3>(sr, si, lm + 48);         // wire 6 -> state bit 3
        rot_local<2>(sr, si, lm + 56);
        rot_local<1>(sr, si, lm + 64);
        rot_local<0>(sr, si, lm + 72);         // wire 9 -> state bit 0
        switch (l) {
            case 0:  ring<1>(sr, si, lane); break;
            case 1:  ring<2>(sr, si, lane); break;
            case 2:  ring<3>(sr, si, lane); break;
            default: ring<4>(sr, si, lane); break;
        }
    }

    // --- expval(PauliZ on wire 9 = state bit 0 = LSB of j) ---
    float acc = 0.0f;
#pragma unroll
    for (int j = 0; j < 16; ++j) {
        const float p = sr[j] * sr[j] + si[j] * si[j];
        acc += (j & 1) ? -p : p;
    }
#pragma unroll
    for (int off = 32; off > 0; off >>= 1) {
        acc += __shfl_xor(acc, off, 64);
    }
    if (lane == 0) out[wave] = acc + bias[0];
}

extern "C" void kernel_launch(void* const* d_in, const int* in_sizes, int n_in,
                              void* d_out, int out_size, void* d_ws, size_t ws_size,
                              hipStream_t stream) {
    const float* X    = (const float*)d_in[0];
    const float* W    = (const float*)d_in[1];
    const float* bias = (const float*)d_in[2];
    float* out = (float*)d_out;
    const int n_samples = in_sizes[0] / NW;          // 16384
    const int threads = 256;                          // 4 waves/block
    const int blocks = (n_samples * 64 + threads - 1) / threads;
    hipLaunchKernelGGL(vqc_kernel, dim3(blocks), dim3(threads), 0, stream,
                       X, W, bias, out, n_samples);
}

// Round 2
// 189.209 us; speedup vs baseline: 1.8408x; 1.8408x over previous
//
#include <hip/hip_runtime.h>
#include <cstdint>
#include <utility>

#define NW 10
#define NL 4

// ============================================================================
// Compile-time plan: CNOT rings are GF(2)-linear index maps. We never move
// data for a CNOT; instead we track M (logical index i = M * physical j) and
// M^{-1}. A rotation on virtual bit b pairs physical {j, j ^ col_b(Minv)} and
// the "which element is |0>" role = parity(j & row_b(M)). Final Z measurement
// = parity(j & row_0(M_final)) sign.
// Lightcone from Z(wire9): layer3 keeps Rot on wires {1,5,9} (ring3 maps
// Z9 -> Z1 Z5 Z9); layer2 drops Rot(wire7). All exact identities.
// ============================================================================

struct Plan {
    int n;
    uint16_t pmask[40];
    uint16_t rmask[40];
    uint8_t  lw[40];
    uint16_t measmask;
};

constexpr bool keep_rot(int l, int w) {
    if (l <= 1) return true;
    if (l == 2) return w != 7;
    return w == 1 || w == 5 || w == 9;   // l == 3
}

constexpr Plan make_plan() {
    Plan P{};
    unsigned row[10], cI[10];
    for (int b = 0; b < 10; ++b) { row[b] = 1u << b; cI[b] = 1u << b; }
    P.n = 0;
    for (int l = 0; l < NL; ++l) {
        for (int w = 0; w < NW; ++w) {
            if (keep_rot(l, w)) {
                const int b = 9 - w;                       // wire w = state bit 9-w
                P.pmask[P.n] = (uint16_t)cI[b];
                P.rmask[P.n] = (uint16_t)row[b];
                P.lw[P.n]    = (uint8_t)(l * NW + w);
                P.n++;
            }
        }
        const int r = l % (NW - 1) + 1;
        for (int w = 0; w < NW; ++w) {                     // ring: CNOT(w, (w+r)%10)
            const int cb = 9 - w, tb = 9 - ((w + r) % NW);
            row[tb] ^= row[cb];                            // M <- C * M
            cI[cb]  ^= cI[tb];                             // Minv <- Minv * C
        }
    }
    P.measmask = (uint16_t)row[0];                         // Z on virtual bit 0 (wire 9)
    return P;
}

constexpr Plan PL = make_plan();
constexpr int NROT = 32;
static_assert(PL.n == NROT, "plan size mismatch");

// one masked-pair rotation; SU(2): u11=conj(u00), u10=-conj(u01) -> role flip
// only negates (m00i, m01r). m = {m00r, m00i, m01r, m01i}.
template<int G>
__device__ __forceinline__ void apply_rot(float (&sr)[16], float (&si)[16],
                                          const float4* __restrict__ rotm, int lane) {
    constexpr unsigned pm = PL.pmask[G], rm = PL.rmask[G];
    constexpr int pLoc = pm & 15, pLane = (int)(pm >> 4);
    constexpr int rLoc = rm & 15, rLane = (int)(rm >> 4);
    const float4 m = rotm[PL.lw[G]];
    const bool rl = (__popc(lane & rLane) & 1) != 0;       // runtime lane role
    const float cmr = m.x, coi = m.w;
    const float bmi = rl ? -m.y : m.y;                     // signed m00i (role 0 of this lane)
    const float bor = rl ? -m.z : m.z;                     // signed m01r

    if constexpr (pLane != 0) {
        if constexpr (pLoc == 0) {
            // partner = same slot, other lane
#pragma unroll
            for (int j = 0; j < 16; ++j) {
                const float pr = __shfl_xor(sr[j], pLane, 64);
                const float pi_ = __shfl_xor(si[j], pLane, 64);
                const float xr = sr[j], xi = si[j];
                if ((__builtin_popcount(j & rLoc) & 1) == 0) {
                    sr[j] = cmr*xr - bmi*xi + bor*pr - coi*pi_;
                    si[j] = cmr*xi + bmi*xr + bor*pi_ + coi*pr;
                } else {
                    sr[j] = cmr*xr + bmi*xi - bor*pr - coi*pi_;
                    si[j] = cmr*xi - bmi*xr - bor*pi_ + coi*pr;
                }
            }
        } else {
            // partner = slot j^pLoc in lane^pLane; process pairs in-place
#pragma unroll
            for (int j = 0; j < 16; ++j) {
                const int k = j ^ pLoc;
                if (j < k) {
                    const float pjr = __shfl_xor(sr[k], pLane, 64);
                    const float pji = __shfl_xor(si[k], pLane, 64);
                    const float pkr = __shfl_xor(sr[j], pLane, 64);
                    const float pki = __shfl_xor(si[j], pLane, 64);
                    const float xjr = sr[j], xji = si[j];
                    const float xkr = sr[k], xki = si[k];
                    if ((__builtin_popcount(j & rLoc) & 1) == 0) {
                        sr[j] = cmr*xjr - bmi*xji + bor*pjr - coi*pji;
                        si[j] = cmr*xji + bmi*xjr + bor*pji + coi*pjr;
                    } else {
                        sr[j] = cmr*xjr + bmi*xji - bor*pjr - coi*pji;
                        si[j] = cmr*xji - bmi*xjr - bor*pji + coi*pjr;
                    }
                    if ((__builtin_popcount(k & rLoc) & 1) == 0) {
                        sr[k] = cmr*xkr - bmi*xki + bor*pkr - coi*pki;
                        si[k] = cmr*xki + bmi*xkr + bor*pki + coi*pkr;
                    } else {
                        sr[k] = cmr*xkr + bmi*xki - bor*pkr - coi*pki;
                        si[k] = cmr*xki - bmi*xkr - bor*pki + coi*pkr;
                    }
                }
            }
        }
    } else {
        // fully local pair
#pragma unroll
        for (int j = 0; j < 16; ++j) {
            const int k = j ^ pLoc;
            if (j < k) {
                const float xjr = sr[j], xji = si[j];
                const float xkr = sr[k], xki = si[k];
                if ((__builtin_popcount(j & rLoc) & 1) == 0) {
                    sr[j] = cmr*xjr - bmi*xji + bor*xkr - coi*xki;
                    si[j] = cmr*xji + bmi*xjr + bor*xki + coi*xkr;
                } else {
                    sr[j] = cmr*xjr + bmi*xji - bor*xkr - coi*xki;
                    si[j] = cmr*xji - bmi*xjr - bor*xki + coi*xkr;
                }
                if ((__builtin_popcount(k & rLoc) & 1) == 0) {
                    sr[k] = cmr*xkr - bmi*xki + bor*xjr - coi*xji;
                    si[k] = cmr*xki + bmi*xkr + bor*xji + coi*xjr;
                } else {
                    sr[k] = cmr*xkr + bmi*xki - bor*xjr - coi*xji;
                    si[k] = cmr*xki - bmi*xkr - bor*xji + coi*xjr;
                }
            }
        }
    }
}

template<int... Gs>
__device__ __forceinline__ void apply_all(float (&sr)[16], float (&si)[16],
                                          const float4* __restrict__ rotm, int lane,
                                          std::integer_sequence<int, Gs...>) {
    (apply_rot<Gs>(sr, si, rotm, lane), ...);
}

__global__ __launch_bounds__(256) void vqc_kernel(const float* __restrict__ X,
                                                  const float* __restrict__ W,
                                                  const float* __restrict__ bias,
                                                  float* __restrict__ out,
                                                  int n_samples) {
    __shared__ float4 rotm[NL * NW];
    const int t = threadIdx.x;

    // per-block Rot coefficient prep: only m00, m01 needed (SU(2))
    if (t < NL * NW) {
        const float phi = W[t * 3 + 0], th = W[t * 3 + 1], om = W[t * 3 + 2];
        float sh, ch; sincosf(0.5f * th, &sh, &ch);
        float s0, c0; sincosf(-0.5f * (phi + om), &s0, &c0);   // e^{-i(phi+om)/2}
        float s1, c1; sincosf( 0.5f * (phi - om), &s1, &c1);   // e^{+i(phi-om)/2}
        rotm[t] = make_float4(c0 * ch, s0 * ch, -c1 * sh, -s1 * sh);
    }
    __syncthreads();

    const int wave = (blockIdx.x * blockDim.x + t) >> 6;   // one wave per sample
    const int lane = t & 63;
    if (wave >= n_samples) return;

    // angle encoding RY(x*pi/2) on |0..0> = real product state (M = I here)
    const float* xp = X + wave * NW;
    float cw[NW], sw[NW];
#pragma unroll
    for (int w = 0; w < NW; ++w) {
        __sincosf(xp[w] * 0.78539816339744831f, &sw[w], &cw[w]);
    }
    float sr[16], si[16];
#pragma unroll
    for (int j = 0; j < 16; ++j) {
        const int idx = (lane << 4) | j;
        float p = 1.0f;
#pragma unroll
        for (int w = 0; w < NW; ++w) {
            p *= ((idx >> (9 - w)) & 1) ? sw[w] : cw[w];
        }
        sr[j] = p; si[j] = 0.0f;
    }

    // all 32 surviving rotations; CNOTs are compile-time index-map updates
    apply_all(sr, si, rotm, lane, std::make_integer_sequence<int, NROT>{});

    // measurement: sign = parity(j_full & measmask)
    constexpr unsigned mm = PL.measmask;
    constexpr int mLoc = mm & 15, mLane = (int)(mm >> 4);
    float acc = 0.0f;
#pragma unroll
    for (int j = 0; j < 16; ++j) {
        const float p = sr[j] * sr[j] + si[j] * si[j];
        acc += ((__builtin_popcount(j & mLoc) & 1) ? -p : p);
    }
    if (__popc(lane & mLane) & 1) acc = -acc;
#pragma unroll
    for (int off = 32; off > 0; off >>= 1) {
        acc += __shfl_xor(acc, off, 64);
    }
    if (lane == 0) out[wave] = acc + bias[0];
}

extern "C" void kernel_launch(void* const* d_in, const int* in_sizes, int n_in,
                              void* d_out, int out_size, void* d_ws, size_t ws_size,
                              hipStream_t stream) {
    const float* X    = (const float*)d_in[0];
    const float* W    = (const float*)d_in[1];
    const float* bias = (const float*)d_in[2];
    float* out = (float*)d_out;
    const int n_samples = in_sizes[0] / NW;               // 16384
    const int threads = 256;                              // 4 waves/block
    const int blocks = (n_samples * 64 + threads - 1) / threads;
    hipLaunchKernelGGL(vqc_kernel, dim3(blocks), dim3(threads), 0, stream,
                       X, W, bias, out, n_samples);
}

// Round 3
// 159.051 us; speedup vs baseline: 2.1898x; 1.1896x over previous
//
#include <hip/hip_runtime.h>
#include <cstdint>
#include <utility>

#define NW 10
#define NL 4

// ============================================================================
// Round 3:
//  - CNOT rings tracked as compile-time GF(2) index maps (round 2).
//  - Lightcone: layer3 keeps Rot{1,5,9}, layer2 drops Rot(7) (round 2).
//  - NEW: encoding RYs + ALL layer-0 Rots form a product state
//    ⊗_w (Rot_w · RY(x_w*pi/2)|0>) -> built directly via a hoisted complex
//    product tree (33 cmults) instead of 10 full gate applications.
//    22 rotations remain in the main loop.
// ============================================================================

struct Plan {
    int n;
    uint16_t pmask[40];
    uint16_t rmask[40];
    uint8_t  lw[40];
    uint16_t measmask;
};

constexpr bool keep_rot(int l, int w) {
    if (l <= 1) return true;
    if (l == 2) return w != 7;
    return w == 1 || w == 5 || w == 9;   // l == 3
}

constexpr Plan make_plan() {
    Plan P{};
    unsigned row[10], cI[10];
    for (int b = 0; b < 10; ++b) { row[b] = 1u << b; cI[b] = 1u << b; }
    P.n = 0;
    for (int l = 0; l < NL; ++l) {
        for (int w = 0; w < NW; ++w) {
            if (l > 0 && keep_rot(l, w)) {          // layer-0 Rots folded into init
                const int b = 9 - w;                // wire w = state bit 9-w
                P.pmask[P.n] = (uint16_t)cI[b];
                P.rmask[P.n] = (uint16_t)row[b];
                P.lw[P.n]    = (uint8_t)(l * NW + w);
                P.n++;
            }
        }
        const int r = l % (NW - 1) + 1;
        for (int w = 0; w < NW; ++w) {              // ring: CNOT(w, (w+r)%10)
            const int cb = 9 - w, tb = 9 - ((w + r) % NW);
            row[tb] ^= row[cb];                     // M <- C * M
            cI[cb]  ^= cI[tb];                      // Minv <- Minv * C
        }
    }
    P.measmask = (uint16_t)row[0];                  // Z on virtual bit 0 (wire 9)
    return P;
}

constexpr Plan PL = make_plan();
constexpr int NROT = 22;
static_assert(PL.n == NROT, "plan size mismatch");

__device__ __forceinline__ void cmul(float ar, float ai, float br, float bi,
                                     float& cr, float& ci) {
    cr = ar * br - ai * bi;
    ci = ar * bi + ai * br;
}

// one masked-pair rotation; SU(2): u11=conj(u00), u10=-conj(u01) -> role flip
// only negates (m00i, m01r). m = {m00r, m00i, m01r, m01i}.
template<int G>
__device__ __forceinline__ void apply_rot(float (&sr)[16], float (&si)[16],
                                          const float4* __restrict__ rotm, int lane) {
    constexpr unsigned pm = PL.pmask[G], rm = PL.rmask[G];
    constexpr int pLoc = pm & 15, pLane = (int)(pm >> 4);
    constexpr int rLoc = rm & 15, rLane = (int)(rm >> 4);
    const float4 m = rotm[PL.lw[G]];
    const bool rl = (__popc(lane & rLane) & 1) != 0;       // runtime lane role
    const float cmr = m.x, coi = m.w;
    const float bmi = rl ? -m.y : m.y;                     // signed m00i (role 0 of this lane)
    const float bor = rl ? -m.z : m.z;                     // signed m01r

    if constexpr (pLane != 0) {
        if constexpr (pLoc == 0) {
#pragma unroll
            for (int j = 0; j < 16; ++j) {
                const float pr  = __shfl_xor(sr[j], pLane, 64);
                const float pi_ = __shfl_xor(si[j], pLane, 64);
                const float xr = sr[j], xi = si[j];
                if ((__builtin_popcount(j & rLoc) & 1) == 0) {
                    sr[j] = cmr*xr - bmi*xi + bor*pr - coi*pi_;
                    si[j] = cmr*xi + bmi*xr + bor*pi_ + coi*pr;
                } else {
                    sr[j] = cmr*xr + bmi*xi - bor*pr - coi*pi_;
                    si[j] = cmr*xi - bmi*xr - bor*pi_ + coi*pr;
                }
            }
        } else {
#pragma unroll
            for (int j = 0; j < 16; ++j) {
                const int k = j ^ pLoc;
                if (j < k) {
                    const float pjr = __shfl_xor(sr[k], pLane, 64);
                    const float pji = __shfl_xor(si[k], pLane, 64);
                    const float pkr = __shfl_xor(sr[j], pLane, 64);
                    const float pki = __shfl_xor(si[j], pLane, 64);
                    const float xjr = sr[j], xji = si[j];
                    const float xkr = sr[k], xki = si[k];
                    if ((__builtin_popcount(j & rLoc) & 1) == 0) {
                        sr[j] = cmr*xjr - bmi*xji + bor*pjr - coi*pji;
                        si[j] = cmr*xji + bmi*xjr + bor*pji + coi*pjr;
                    } else {
                        sr[j] = cmr*xjr + bmi*xji - bor*pjr - coi*pji;
                        si[j] = cmr*xji - bmi*xjr - bor*pji + coi*pjr;
                    }
                    if ((__builtin_popcount(k & rLoc) & 1) == 0) {
                        sr[k] = cmr*xkr - bmi*xki + bor*pkr - coi*pki;
                        si[k] = cmr*xki + bmi*xkr + bor*pki + coi*pkr;
                    } else {
                        sr[k] = cmr*xkr + bmi*xki - bor*pkr - coi*pki;
                        si[k] = cmr*xki - bmi*xkr - bor*pki + coi*pkr;
                    }
                }
            }
        }
    } else {
#pragma unroll
        for (int j = 0; j < 16; ++j) {
            const int k = j ^ pLoc;
            if (j < k) {
                const float xjr = sr[j], xji = si[j];
                const float xkr = sr[k], xki = si[k];
                if ((__builtin_popcount(j & rLoc) & 1) == 0) {
                    sr[j] = cmr*xjr - bmi*xji + bor*xkr - coi*xki;
                    si[j] = cmr*xji + bmi*xjr + bor*xki + coi*xkr;
                } else {
                    sr[j] = cmr*xjr + bmi*xji - bor*xkr - coi*xki;
                    si[j] = cmr*xji - bmi*xjr - bor*xki + coi*xkr;
                }
                if ((__builtin_popcount(k & rLoc) & 1) == 0) {
                    sr[k] = cmr*xkr - bmi*xki + bor*xjr - coi*xji;
                    si[k] = cmr*xki + bmi*xkr + bor*xji + coi*xjr;
                } else {
                    sr[k] = cmr*xkr + bmi*xki - bor*xjr - coi*xji;
                    si[k] = cmr*xki - bmi*xkr - bor*xji + coi*xjr;
                }
            }
        }
    }
}

template<int... Gs>
__device__ __forceinline__ void apply_all(float (&sr)[16], float (&si)[16],
                                          const float4* __restrict__ rotm, int lane,
                                          std::integer_sequence<int, Gs...>) {
    (apply_rot<Gs>(sr, si, rotm, lane), ...);
}

__global__ __launch_bounds__(256) void vqc_kernel(const float* __restrict__ X,
                                                  const float* __restrict__ W,
                                                  const float* __restrict__ bias,
                                                  float* __restrict__ out,
                                                  int n_samples) {
    __shared__ float4 rotm[NL * NW];
    const int t = threadIdx.x;

    // per-block Rot coefficient prep: only m00, m01 needed (SU(2))
    if (t < NL * NW) {
        const float phi = W[t * 3 + 0], th = W[t * 3 + 1], om = W[t * 3 + 2];
        float sh, ch; sincosf(0.5f * th, &sh, &ch);
        float s0, c0; sincosf(-0.5f * (phi + om), &s0, &c0);   // e^{-i(phi+om)/2}
        float s1, c1; sincosf( 0.5f * (phi - om), &s1, &c1);   // e^{+i(phi-om)/2}
        rotm[t] = make_float4(c0 * ch, s0 * ch, -c1 * sh, -s1 * sh);
    }
    __syncthreads();

    const int wave = (blockIdx.x * blockDim.x + t) >> 6;   // one wave per sample
    const int lane = t & 63;
    if (wave >= n_samples) return;

    // ---- product-state init: per-wire 2-vector v_w = Rot0_w * RY(x_w*pi/2)|0> ----
    // m00=m.x+i m.y, m01=m.z+i m.w, m10=-m.z+i m.w, m11=m.x-i m.y
    const float* xp = X + wave * NW;
    float v0r[NW], v0i[NW], v1r[NW], v1i[NW];
#pragma unroll
    for (int w = 0; w < NW; ++w) {
        float s, c;
        __sincosf(xp[w] * 0.78539816339744831f, &s, &c);   // half-angle = x*pi/4
        const float4 m = rotm[w];                          // layer 0
        v0r[w] =  m.x * c + m.z * s;
        v0i[w] =  m.y * c + m.w * s;
        v1r[w] = -m.z * c + m.x * s;
        v1i[w] =  m.w * c - m.y * s;
    }
    // lane product H over wires 0..5 (wire w -> lane bit 5-w)
    float hr, hi;
    {
        const bool b0 = (lane >> 5) & 1;
        hr = b0 ? v1r[0] : v0r[0];
        hi = b0 ? v1i[0] : v0i[0];
#pragma unroll
        for (int w = 1; w < 6; ++w) {
            const bool b = (lane >> (5 - w)) & 1;
            const float br = b ? v1r[w] : v0r[w];
            const float bi = b ? v1i[w] : v0i[w];
            float nr, ni; cmul(hr, hi, br, bi, nr, ni);
            hr = nr; hi = ni;
        }
    }
    // local tables: A over wires 6,7 (j bits 3,2), B over wires 8,9 (j bits 1,0)
    float Ar[4], Ai[4], Br[4], Bi[4];
#pragma unroll
    for (int u = 0; u < 4; ++u) {
        const int b6 = (u >> 1) & 1, b7 = u & 1;
        cmul(b6 ? v1r[6] : v0r[6], b6 ? v1i[6] : v0i[6],
             b7 ? v1r[7] : v0r[7], b7 ? v1i[7] : v0i[7], Ar[u], Ai[u]);
        const int b8 = (u >> 1) & 1, b9 = u & 1;
        cmul(b8 ? v1r[8] : v0r[8], b8 ? v1i[8] : v0i[8],
             b9 ? v1r[9] : v0r[9], b9 ? v1i[9] : v0i[9], Br[u], Bi[u]);
    }
    // HA = H*A (4 cmults), then state = HA[j>>2] * B[j&3]
    float HAr[4], HAi[4];
#pragma unroll
    for (int u = 0; u < 4; ++u) cmul(hr, hi, Ar[u], Ai[u], HAr[u], HAi[u]);

    float sr[16], si[16];
#pragma unroll
    for (int j = 0; j < 16; ++j) {
        cmul(HAr[j >> 2], HAi[j >> 2], Br[j & 3], Bi[j & 3], sr[j], si[j]);
    }

    // ---- 22 surviving rotations (layers 1..3); CNOTs are index-map updates ----
    apply_all(sr, si, rotm, lane, std::make_integer_sequence<int, NROT>{});

    // ---- measurement: sign = parity(j_full & measmask) ----
    constexpr unsigned mm = PL.measmask;
    constexpr int mLoc = mm & 15, mLane = (int)(mm >> 4);
    float acc = 0.0f;
#pragma unroll
    for (int j = 0; j < 16; ++j) {
        const float p = sr[j] * sr[j] + si[j] * si[j];
        acc += ((__builtin_popcount(j & mLoc) & 1) ? -p : p);
    }
    if (__popc(lane & mLane) & 1) acc = -acc;
#pragma unroll
    for (int off = 32; off > 0; off >>= 1) {
        acc += __shfl_xor(acc, off, 64);
    }
    if (lane == 0) out[wave] = acc + bias[0];
}

extern "C" void kernel_launch(void* const* d_in, const int* in_sizes, int n_in,
                              void* d_out, int out_size, void* d_ws, size_t ws_size,
                              hipStream_t stream) {
    const float* X    = (const float*)d_in[0];
    const float* W    = (const float*)d_in[1];
    const float* bias = (const float*)d_in[2];
    float* out = (float*)d_out;
    const int n_samples = in_sizes[0] / NW;               // 16384
    const int threads = 256;                              // 4 waves/block
    const int blocks = (n_samples * 64 + threads - 1) / threads;
    hipLaunchKernelGGL(vqc_kernel, dim3(blocks), dim3(threads), 0, stream,
                       X, W, bias, out, n_samples);
}

// Round 4
// 131.817 us; speedup vs baseline: 2.6422x; 1.2066x over previous
//
#include <hip/hip_runtime.h>
#include <cstdint>
#include <utility>

#define NW 10
#define NL 4

// ============================================================================
// Round 4:
//  - CNOT rings tracked as compile-time GF(2) index maps (round 2).
//  - Lightcone: layer3 keeps Rot{1,5,9}, layer2 drops Rot(7) (round 2).
//  - Product-state init folds encoding RYs + all layer-0 Rots (round 3).
//  - NEW: cross-lane exchange via direct ds_swizzle (immediate xor pattern,
//    masks <32: 11 of 18 cross gates) / ds_bpermute (precomputed byte addr,
//    masks >=32: 7 gates) instead of HIP __shfl_xor's per-call addr math.
// ============================================================================

struct Plan {
    int n;
    uint16_t pmask[40];
    uint16_t rmask[40];
    uint8_t  lw[40];
    uint16_t measmask;
};

constexpr bool keep_rot(int l, int w) {
    if (l <= 1) return true;
    if (l == 2) return w != 7;
    return w == 1 || w == 5 || w == 9;   // l == 3
}

constexpr Plan make_plan() {
    Plan P{};
    unsigned row[10], cI[10];
    for (int b = 0; b < 10; ++b) { row[b] = 1u << b; cI[b] = 1u << b; }
    P.n = 0;
    for (int l = 0; l < NL; ++l) {
        for (int w = 0; w < NW; ++w) {
            if (l > 0 && keep_rot(l, w)) {          // layer-0 Rots folded into init
                const int b = 9 - w;                // wire w = state bit 9-w
                P.pmask[P.n] = (uint16_t)cI[b];
                P.rmask[P.n] = (uint16_t)row[b];
                P.lw[P.n]    = (uint8_t)(l * NW + w);
                P.n++;
            }
        }
        const int r = l % (NW - 1) + 1;
        for (int w = 0; w < NW; ++w) {              // ring: CNOT(w, (w+r)%10)
            const int cb = 9 - w, tb = 9 - ((w + r) % NW);
            row[tb] ^= row[cb];                     // M <- C * M
            cI[cb]  ^= cI[tb];                      // Minv <- Minv * C
        }
    }
    P.measmask = (uint16_t)row[0];                  // Z on virtual bit 0 (wire 9)
    return P;
}

constexpr Plan PL = make_plan();
constexpr int NROT = 22;
static_assert(PL.n == NROT, "plan size mismatch");

// cross-lane xor exchange: immediate ds_swizzle for masks <32 (xor within
// 32-lane groups == global xor for mask<32); ds_bpermute for masks >=32.
template<int MASK>
__device__ __forceinline__ float lane_xor(float v, int lane4 /* lane<<2 */) {
    if constexpr (MASK == 0) {
        return v;
    } else if constexpr (MASK < 32) {
        return __int_as_float(__builtin_amdgcn_ds_swizzle(
            __float_as_int(v), (MASK << 10) | 0x1F));       // bit-mode xor pattern
    } else {
        return __int_as_float(__builtin_amdgcn_ds_bpermute(
            lane4 ^ (MASK << 2), __float_as_int(v)));
    }
}

__device__ __forceinline__ void cmul(float ar, float ai, float br, float bi,
                                     float& cr, float& ci) {
    cr = ar * br - ai * bi;
    ci = ar * bi + ai * br;
}

// one masked-pair rotation; SU(2): u11=conj(u00), u10=-conj(u01) -> role flip
// only negates (m00i, m01r). m = {m00r, m00i, m01r, m01i}.
template<int G>
__device__ __forceinline__ void apply_rot(float (&sr)[16], float (&si)[16],
                                          const float4* __restrict__ rotm,
                                          int lane, int lane4) {
    constexpr unsigned pm = PL.pmask[G], rm = PL.rmask[G];
    constexpr int pLoc = pm & 15, pLane = (int)(pm >> 4);
    constexpr int rLoc = rm & 15, rLane = (int)(rm >> 4);
    const float4 m = rotm[PL.lw[G]];
    const bool rl = (__popc(lane & rLane) & 1) != 0;       // runtime lane role
    const float cmr = m.x, coi = m.w;
    const float bmi = rl ? -m.y : m.y;                     // signed m00i (role 0 of this lane)
    const float bor = rl ? -m.z : m.z;                     // signed m01r

    if constexpr (pLane != 0) {
        if constexpr (pLoc == 0) {
#pragma unroll
            for (int j = 0; j < 16; ++j) {
                const float pr  = lane_xor<pLane>(sr[j], lane4);
                const float pi_ = lane_xor<pLane>(si[j], lane4);
                const float xr = sr[j], xi = si[j];
                if ((__builtin_popcount(j & rLoc) & 1) == 0) {
                    sr[j] = cmr*xr - bmi*xi + bor*pr - coi*pi_;
                    si[j] = cmr*xi + bmi*xr + bor*pi_ + coi*pr;
                } else {
                    sr[j] = cmr*xr + bmi*xi - bor*pr - coi*pi_;
                    si[j] = cmr*xi - bmi*xr - bor*pi_ + coi*pr;
                }
            }
        } else {
#pragma unroll
            for (int j = 0; j < 16; ++j) {
                const int k = j ^ pLoc;
                if (j < k) {
                    const float pjr = lane_xor<pLane>(sr[k], lane4);
                    const float pji = lane_xor<pLane>(si[k], lane4);
                    const float pkr = lane_xor<pLane>(sr[j], lane4);
                    const float pki = lane_xor<pLane>(si[j], lane4);
                    const float xjr = sr[j], xji = si[j];
                    const float xkr = sr[k], xki = si[k];
                    if ((__builtin_popcount(j & rLoc) & 1) == 0) {
                        sr[j] = cmr*xjr - bmi*xji + bor*pjr - coi*pji;
                        si[j] = cmr*xji + bmi*xjr + bor*pji + coi*pjr;
                    } else {
                        sr[j] = cmr*xjr + bmi*xji - bor*pjr - coi*pji;
                        si[j] = cmr*xji - bmi*xjr - bor*pji + coi*pjr;
                    }
                    if ((__builtin_popcount(k & rLoc) & 1) == 0) {
                        sr[k] = cmr*xkr - bmi*xki + bor*pkr - coi*pki;
                        si[k] = cmr*xki + bmi*xkr + bor*pki + coi*pkr;
                    } else {
                        sr[k] = cmr*xkr + bmi*xki - bor*pkr - coi*pki;
                        si[k] = cmr*xki - bmi*xkr - bor*pki + coi*pkr;
                    }
                }
            }
        }
    } else {
#pragma unroll
        for (int j = 0; j < 16; ++j) {
            const int k = j ^ pLoc;
            if (j < k) {
                const float xjr = sr[j], xji = si[j];
                const float xkr = sr[k], xki = si[k];
                if ((__builtin_popcount(j & rLoc) & 1) == 0) {
                    sr[j] = cmr*xjr - bmi*xji + bor*xkr - coi*xki;
                    si[j] = cmr*xji + bmi*xjr + bor*xki + coi*xkr;
                } else {
                    sr[j] = cmr*xjr + bmi*xji - bor*xkr - coi*xki;
                    si[j] = cmr*xji - bmi*xjr - bor*xki + coi*xkr;
                }
                if ((__builtin_popcount(k & rLoc) & 1) == 0) {
                    sr[k] = cmr*xkr - bmi*xki + bor*xjr - coi*xji;
                    si[k] = cmr*xki + bmi*xkr + bor*xji + coi*xjr;
                } else {
                    sr[k] = cmr*xkr + bmi*xki - bor*xjr - coi*xji;
                    si[k] = cmr*xki - bmi*xkr - bor*xji + coi*xjr;
                }
            }
        }
    }
}

template<int... Gs>
__device__ __forceinline__ void apply_all(float (&sr)[16], float (&si)[16],
                                          const float4* __restrict__ rotm,
                                          int lane, int lane4,
                                          std::integer_sequence<int, Gs...>) {
    (apply_rot<Gs>(sr, si, rotm, lane, lane4), ...);
}

__global__ __launch_bounds__(256) void vqc_kernel(const float* __restrict__ X,
                                                  const float* __restrict__ W,
                                                  const float* __restrict__ bias,
                                                  float* __restrict__ out,
                                                  int n_samples) {
    __shared__ float4 rotm[NL * NW];
    const int t = threadIdx.x;

    // per-block Rot coefficient prep: only m00, m01 needed (SU(2))
    if (t < NL * NW) {
        const float phi = W[t * 3 + 0], th = W[t * 3 + 1], om = W[t * 3 + 2];
        float sh, ch; sincosf(0.5f * th, &sh, &ch);
        float s0, c0; sincosf(-0.5f * (phi + om), &s0, &c0);   // e^{-i(phi+om)/2}
        float s1, c1; sincosf( 0.5f * (phi - om), &s1, &c1);   // e^{+i(phi-om)/2}
        rotm[t] = make_float4(c0 * ch, s0 * ch, -c1 * sh, -s1 * sh);
    }
    __syncthreads();

    const int wave = (blockIdx.x * blockDim.x + t) >> 6;   // one wave per sample
    const int lane = t & 63;
    const int lane4 = lane << 2;
    if (wave >= n_samples) return;

    // ---- product-state init: per-wire 2-vector v_w = Rot0_w * RY(x_w*pi/2)|0> ----
    const float* xp = X + wave * NW;
    float v0r[NW], v0i[NW], v1r[NW], v1i[NW];
#pragma unroll
    for (int w = 0; w < NW; ++w) {
        float s, c;
        __sincosf(xp[w] * 0.78539816339744831f, &s, &c);   // half-angle = x*pi/4
        const float4 m = rotm[w];                          // layer 0
        v0r[w] =  m.x * c + m.z * s;
        v0i[w] =  m.y * c + m.w * s;
        v1r[w] = -m.z * c + m.x * s;
        v1i[w] =  m.w * c - m.y * s;
    }
    // lane product H over wires 0..5 (wire w -> lane bit 5-w)
    float hr, hi;
    {
        const bool b0 = (lane >> 5) & 1;
        hr = b0 ? v1r[0] : v0r[0];
        hi = b0 ? v1i[0] : v0i[0];
#pragma unroll
        for (int w = 1; w < 6; ++w) {
            const bool b = (lane >> (5 - w)) & 1;
            const float br = b ? v1r[w] : v0r[w];
            const float bi = b ? v1i[w] : v0i[w];
            float nr, ni; cmul(hr, hi, br, bi, nr, ni);
            hr = nr; hi = ni;
        }
    }
    // local tables: A over wires 6,7 (j bits 3,2), B over wires 8,9 (j bits 1,0)
    float Ar[4], Ai[4], Br[4], Bi[4];
#pragma unroll
    for (int u = 0; u < 4; ++u) {
        const int hb = (u >> 1) & 1, lb = u & 1;
        cmul(hb ? v1r[6] : v0r[6], hb ? v1i[6] : v0i[6],
             lb ? v1r[7] : v0r[7], lb ? v1i[7] : v0i[7], Ar[u], Ai[u]);
        cmul(hb ? v1r[8] : v0r[8], hb ? v1i[8] : v0i[8],
             lb ? v1r[9] : v0r[9], lb ? v1i[9] : v0i[9], Br[u], Bi[u]);
    }
    // HA = H*A (4 cmults), then state = HA[j>>2] * B[j&3]
    float HAr[4], HAi[4];
#pragma unroll
    for (int u = 0; u < 4; ++u) cmul(hr, hi, Ar[u], Ai[u], HAr[u], HAi[u]);

    float sr[16], si[16];
#pragma unroll
    for (int j = 0; j < 16; ++j) {
        cmul(HAr[j >> 2], HAi[j >> 2], Br[j & 3], Bi[j & 3], sr[j], si[j]);
    }

    // ---- 22 surviving rotations (layers 1..3); CNOTs are index-map updates ----
    apply_all(sr, si, rotm, lane, lane4, std::make_integer_sequence<int, NROT>{});

    // ---- measurement: sign = parity(j_full & measmask) ----
    constexpr unsigned mm = PL.measmask;
    constexpr int mLoc = mm & 15, mLane = (int)(mm >> 4);
    float acc = 0.0f;
#pragma unroll
    for (int j = 0; j < 16; ++j) {
        const float p = sr[j] * sr[j] + si[j] * si[j];
        acc += ((__builtin_popcount(j & mLoc) & 1) ? -p : p);
    }
    if (__popc(lane & mLane) & 1) acc = -acc;
    acc += lane_xor<32>(acc, lane4);
    acc += lane_xor<16>(acc, lane4);
    acc += lane_xor<8>(acc, lane4);
    acc += lane_xor<4>(acc, lane4);
    acc += lane_xor<2>(acc, lane4);
    acc += lane_xor<1>(acc, lane4);
    if (lane == 0) out[wave] = acc + bias[0];
}

extern "C" void kernel_launch(void* const* d_in, const int* in_sizes, int n_in,
                              void* d_out, int out_size, void* d_ws, size_t ws_size,
                              hipStream_t stream) {
    const float* X    = (const float*)d_in[0];
    const float* W    = (const float*)d_in[1];
    const float* bias = (const float*)d_in[2];
    float* out = (float*)d_out;
    const int n_samples = in_sizes[0] / NW;               // 16384
    const int threads = 256;                              // 4 waves/block
    const int blocks = (n_samples * 64 + threads - 1) / threads;
    hipLaunchKernelGGL(vqc_kernel, dim3(blocks), dim3(threads), 0, stream,
                       X, W, bias, out, n_samples);
}